// Round 1
// baseline (315.616 us; speedup 1.0000x reference)
//
#include <hip/hip_runtime.h>
#include <hip/hip_bf16.h>

#define B_ 32
#define C_ 1000
#define H_ 512
#define NP 1024   // padded node count (N=1001 real)
#define NMB 64    // 2 modalities * 32 batches

typedef __attribute__((ext_vector_type(8))) short short8;
typedef __attribute__((ext_vector_type(8))) unsigned short ushort8;
typedef __attribute__((ext_vector_type(4))) float f32x4;

__device__ __forceinline__ unsigned short f2bf(float f) {
  unsigned u = __builtin_bit_cast(unsigned, f);
  u += 0x7FFF + ((u >> 16) & 1);
  return (unsigned short)(u >> 16);
}
__device__ __forceinline__ float bf2f(unsigned short h) {
  return __builtin_bit_cast(float, (unsigned)h << 16);
}
__device__ __forceinline__ float tanh_fast(float x) {
  float ax = fminf(fabsf(x), 15.0f);
  float e = __expf(2.0f * ax);
  float t = (e - 1.0f) / (e + 1.0f);
  return copysignf(t, x);
}
__device__ __forceinline__ void gload16(const void* g, void* l) {
  __builtin_amdgcn_global_load_lds((const __attribute__((address_space(1))) unsigned*)g,
                                   (__attribute__((address_space(3))) unsigned*)l, 16, 0, 0);
}

// ---------------- K1: normalize features, write bf16 padded [2][32][1024][512] ----------------
__global__ __launch_bounds__(256) void k_norm(const float* __restrict__ it, const float* __restrict__ ii,
                                              const float* __restrict__ bt, const float* __restrict__ bi,
                                              unsigned short* __restrict__ xn, float* __restrict__ nrm) {
  int wid = blockIdx.x * 4 + (threadIdx.x >> 6);  // one wave per node; wid in [0, 65536)
  int lane = threadIdx.x & 63;
  int node = wid & (NP - 1);
  int mb = wid >> 10;          // mod*32 + b
  int b = mb & 31, mod = mb >> 5;
  const float* src = nullptr;
  if (node == 0) src = (mod ? ii : it) + b * H_;
  else if (node <= C_) src = (mod ? bi : bt) + ((size_t)b * C_ + (node - 1)) * H_;
  float4 v0 = make_float4(0.f, 0.f, 0.f, 0.f), v1 = v0;
  if (src) {
    const float4* s4 = (const float4*)src;
    v0 = s4[lane * 2]; v1 = s4[lane * 2 + 1];
  }
  float ss = v0.x*v0.x + v0.y*v0.y + v0.z*v0.z + v0.w*v0.w
           + v1.x*v1.x + v1.y*v1.y + v1.z*v1.z + v1.w*v1.w;
  #pragma unroll
  for (int o = 32; o; o >>= 1) ss += __shfl_xor(ss, o);
  float n = sqrtf(ss);
  if (lane == 0) nrm[wid] = n;
  float inv = 1.0f / fmaxf(n, 1e-12f);
  ushort8 o;
  o[0] = f2bf(v0.x * inv); o[1] = f2bf(v0.y * inv); o[2] = f2bf(v0.z * inv); o[3] = f2bf(v0.w * inv);
  o[4] = f2bf(v1.x * inv); o[5] = f2bf(v1.y * inv); o[6] = f2bf(v1.z * inv); o[7] = f2bf(v1.w * inv);
  *(ushort8*)(xn + (size_t)wid * H_ + lane * 8) = o;
}

// ---------------- K2: Gram row-sums (clipped) + row 0, per (mod,b) ----------------
// G = Xn · Xnᵀ ; r[m] += Σ_k max(G[m,k],0) ; sc[m] = max(G[0,m],0)
__global__ __launch_bounds__(256) void k_gram(const unsigned short* __restrict__ xn,
                                              float* __restrict__ r, float* __restrict__ sc) {
  __shared__ __align__(16) unsigned short As[128 * 32];
  __shared__ __align__(16) unsigned short Bs[128 * 32];
  int bid = blockIdx.x;
  int tile = bid & 63, mb = bid >> 6;
  int ti = tile >> 3, tj = tile & 7;
  const unsigned short* X = xn + (size_t)mb * NP * H_;
  int tid = threadIdx.x;
  int w = tid >> 6, lane = tid & 63;
  int wr = w >> 1, wc = w & 1;
  f32x4 acc[4][4] = {};

  int lrow = lane >> 2;   // row within 16-row staging chunk
  int ps0 = lane & 3;     // physical 16B segment

  auto stage = [&](int ks) {
    #pragma unroll
    for (int q = 0; q < 2; ++q) {
      int chunk = w * 2 + q;
      int row = chunk * 16 + lrow;
      int qq = ps0 ^ ((row >> 1) & 3);  // logical k-segment stored at this physical slot
      const unsigned short* gA = X + (size_t)(ti * 128 + row) * H_ + ks * 32 + qq * 8;
      gload16(gA, (void*)(As + chunk * 512));
      const unsigned short* gB = X + (size_t)(tj * 128 + row) * H_ + ks * 32 + qq * 8;
      gload16(gB, (void*)(Bs + chunk * 512));
    }
  };

  stage(0);
  for (int ks = 0; ks < 16; ++ks) {
    __syncthreads();   // drains vmcnt: staged tile visible
    short8 af[4], bf[4];
    #pragma unroll
    for (int mi = 0; mi < 4; ++mi) {
      int row = wr * 64 + mi * 16 + (lane & 15);
      int ps = (lane >> 4) ^ ((row >> 1) & 3);
      af[mi] = *(const short8*)(As + row * 32 + ps * 8);
    }
    #pragma unroll
    for (int ni = 0; ni < 4; ++ni) {
      int row = wc * 64 + ni * 16 + (lane & 15);
      int ps = (lane >> 4) ^ ((row >> 1) & 3);
      bf[ni] = *(const short8*)(Bs + row * 32 + ps * 8);
    }
    #pragma unroll
    for (int mi = 0; mi < 4; ++mi)
      #pragma unroll
      for (int ni = 0; ni < 4; ++ni)
        acc[mi][ni] = __builtin_amdgcn_mfma_f32_16x16x32_bf16(af[mi], bf[ni], acc[mi][ni], 0, 0, 0);
    __syncthreads();   // all reads done before overwrite
    if (ks < 15) stage(ks + 1);
  }

  // epilogue: clip, row-sum, atomic accumulate.
  // C/D layout: col = lane&15, row = (lane>>4)*4 + reg  (within each 16x16 frag)
  float* rr = r + mb * NP;
  #pragma unroll
  for (int mi = 0; mi < 4; ++mi) {
    #pragma unroll
    for (int reg = 0; reg < 4; ++reg) {
      float v = fmaxf(acc[mi][0][reg], 0.f) + fmaxf(acc[mi][1][reg], 0.f)
              + fmaxf(acc[mi][2][reg], 0.f) + fmaxf(acc[mi][3][reg], 0.f);
      v += __shfl_xor(v, 1); v += __shfl_xor(v, 2); v += __shfl_xor(v, 4); v += __shfl_xor(v, 8);
      if ((lane & 15) == 0) {
        int row = ti * 128 + wr * 64 + mi * 16 + (lane >> 4) * 4 + reg;
        atomicAdd(&rr[row], v);
      }
    }
  }
  if (ti == 0 && wr == 0 && (lane >> 4) == 0) {
    float* scc = sc + mb * NP;
    #pragma unroll
    for (int ni = 0; ni < 4; ++ni) {
      int col = tj * 128 + wc * 64 + ni * 16 + (lane & 15);
      scc[col] = fmaxf(acc[0][ni][0], 0.f);   // row 0 of G
    }
  }
}

// ---------------- K3a: per-node weights w[m] = d0*dm*(sc[m]+[m==0])*norm[m] ----------------
__global__ void k_weights(const float* __restrict__ r, const float* __restrict__ sc,
                          const float* __restrict__ nrm, float* __restrict__ w) {
  int mb = blockIdx.x;
  const float* rr = r + mb * NP; const float* scc = sc + mb * NP;
  const float* nn = nrm + mb * NP; float* ww = w + mb * NP;
  float d0 = rsqrtf(rr[0] + 1.0f);
  for (int i = threadIdx.x; i < NP; i += blockDim.x) {
    float dm = rsqrtf(rr[i] + 1.0f);
    float a = scc[i] + (i == 0 ? 1.0f : 0.0f);
    ww[i] = d0 * dm * a * nn[i];
  }
}

// ---------------- K3b: y[mb][h] = Σ_m w[m] * xn[mb][m][h] (x_m = xn_m * norm_m folded into w) ----------------
__global__ __launch_bounds__(256) void k_y(const unsigned short* __restrict__ xn,
                                           const float* __restrict__ w, float* __restrict__ y) {
  int bid = blockIdx.x;
  int chunk = bid & 7, mb = bid >> 3;
  int m0 = chunk * 128;
  int m1 = min(m0 + 128, 1001);
  int t = threadIdx.x;
  const unsigned short* X = xn + (size_t)mb * NP * H_ + t * 2;
  const float* ww = w + mb * NP;
  float a0 = 0.f, a1 = 0.f;
  for (int m = m0; m < m1; ++m) {
    float wm = ww[m];
    unsigned u = *(const unsigned*)(X + (size_t)m * H_);
    a0 += wm * bf2f((unsigned short)(u & 0xffff));
    a1 += wm * bf2f((unsigned short)(u >> 16));
  }
  atomicAdd(&y[mb * H_ + 2 * t], a0);
  atomicAdd(&y[mb * H_ + 2 * t + 1], a1);
}

// ---------------- K4: graph_o[b][k] = 0.7*tanh(y_ttᵀW_tt + b_tt[0]) + 0.3*tanh(y_itᵀW_it + b_it[0]) ----------------
__global__ __launch_bounds__(256) void k_go(const float* __restrict__ y,
                                            const float* __restrict__ Wtt, const float* __restrict__ btt,
                                            const float* __restrict__ Wit, const float* __restrict__ bit,
                                            float* __restrict__ go) {
  int b = blockIdx.x, t = threadIdx.x;
  const float* ytt = y + b * H_;
  const float* yit = y + (32 + b) * H_;
  for (int k = t; k < H_; k += 256) {
    float att = btt[k], ait = bit[k];
    for (int h = 0; h < H_; ++h) {
      att = fmaf(ytt[h], Wtt[h * H_ + k], att);
      ait = fmaf(yit[h], Wit[h * H_ + k], ait);
    }
    go[b * H_ + k] = 0.7f * tanh_fast(att) + 0.3f * tanh_fast(ait);
  }
}

// ---------------- K5: out = 0.5*base + 0.5*graph_o (broadcast over C) ----------------
__global__ __launch_bounds__(256) void k_out(const float* __restrict__ bt, const float* __restrict__ bi,
                                             const float* __restrict__ go, float* __restrict__ out) {
  const float4* bt4 = (const float4*)bt;
  const float4* bi4 = (const float4*)bi;
  const float4* go4 = (const float4*)go;
  float4* o4 = (float4*)out;
  const int n1 = B_ * C_ * (H_ / 4);   // 4,096,000
  int stride = gridDim.x * blockDim.x;
  for (int i = blockIdx.x * blockDim.x + threadIdx.x; i < 2 * n1; i += stride) {
    int v = (i >= n1) ? i - n1 : i;
    float4 base = (i >= n1) ? bi4[v] : bt4[v];
    int b = v / (C_ * (H_ / 4));
    int h4 = v & (H_ / 4 - 1);
    float4 g = go4[b * (H_ / 4) + h4];
    float4 o;
    o.x = 0.5f * (base.x + g.x);
    o.y = 0.5f * (base.y + g.y);
    o.z = 0.5f * (base.z + g.z);
    o.w = 0.5f * (base.w + g.w);
    o4[i] = o;
  }
}

extern "C" void kernel_launch(void* const* d_in, const int* in_sizes, int n_in,
                              void* d_out, int out_size, void* d_ws, size_t ws_size,
                              hipStream_t stream) {
  const float* it  = (const float*)d_in[0];
  const float* ii  = (const float*)d_in[1];
  const float* bt  = (const float*)d_in[2];
  const float* bi  = (const float*)d_in[3];
  const float* Wtt = (const float*)d_in[4];
  const float* btt = (const float*)d_in[5];
  const float* Wit = (const float*)d_in[6];
  const float* bit = (const float*)d_in[7];

  char* ws = (char*)d_ws;
  unsigned short* xn = (unsigned short*)ws;                       // 2*32*1024*512*2 = 67,108,864 B
  size_t off = 67108864;
  float* nrm = (float*)(ws + off); off += 262144;                 // [2][32][1024] f32
  float* sc  = (float*)(ws + off); off += 262144;
  float* wv  = (float*)(ws + off); off += 262144;
  float* go  = (float*)(ws + off); off += 65536;                  // [32][512]
  float* r   = (float*)(ws + off); off += 262144;                 // needs zeroing
  float* y   = (float*)(ws + off); off += 131072;                 // needs zeroing (contiguous with r)

  hipMemsetAsync(r, 0, 262144 + 131072, stream);

  k_norm<<<16384, 256, 0, stream>>>(it, ii, bt, bi, xn, nrm);
  k_gram<<<4096, 256, 0, stream>>>(xn, r, sc);
  k_weights<<<64, 256, 0, stream>>>(r, sc, nrm, wv);
  k_y<<<512, 256, 0, stream>>>(xn, wv, y);
  k_go<<<32, 256, 0, stream>>>(y, Wtt, btt, Wit, bit, go);
  k_out<<<2048, 256, 0, stream>>>(bt, bi, go, (float*)d_out);
}

// Round 2
// 219.597 us; speedup vs baseline: 1.4373x; 1.4373x over previous
//
#include <hip/hip_runtime.h>
#include <hip/hip_bf16.h>

#define B_ 32
#define C_ 1000
#define H_ 512
#define NP 1024   // padded node count (N=1001 real)

typedef __attribute__((ext_vector_type(8))) short short8;
typedef __attribute__((ext_vector_type(8))) unsigned short ushort8;
typedef __attribute__((ext_vector_type(4))) float f32x4;

__device__ __forceinline__ unsigned short f2bf(float f) {
  unsigned u = __builtin_bit_cast(unsigned, f);
  u += 0x7FFF + ((u >> 16) & 1);
  return (unsigned short)(u >> 16);
}
__device__ __forceinline__ float bf2f(unsigned short h) {
  return __builtin_bit_cast(float, (unsigned)h << 16);
}
__device__ __forceinline__ float tanh_fast(float x) {
  float ax = fminf(fabsf(x), 15.0f);
  float e = __expf(2.0f * ax);
  float t = (e - 1.0f) / (e + 1.0f);
  return copysignf(t, x);
}
__device__ __forceinline__ void gload16(const void* g, void* l) {
  __builtin_amdgcn_global_load_lds((const __attribute__((address_space(1))) unsigned*)g,
                                   (__attribute__((address_space(3))) unsigned*)l, 16, 0, 0);
}

// ---------------- K1: normalize features, write bf16 padded [2][32][1024][512] ----------------
__global__ __launch_bounds__(256) void k_norm(const float* __restrict__ it, const float* __restrict__ ii,
                                              const float* __restrict__ bt, const float* __restrict__ bi,
                                              unsigned short* __restrict__ xn, float* __restrict__ nrm) {
  int wid = blockIdx.x * 4 + (threadIdx.x >> 6);  // one wave per node; wid in [0, 65536)
  int lane = threadIdx.x & 63;
  int node = wid & (NP - 1);
  int mb = wid >> 10;          // mod*32 + b
  int b = mb & 31, mod = mb >> 5;
  const float* src = nullptr;
  if (node == 0) src = (mod ? ii : it) + b * H_;
  else if (node <= C_) src = (mod ? bi : bt) + ((size_t)b * C_ + (node - 1)) * H_;
  float4 v0 = make_float4(0.f, 0.f, 0.f, 0.f), v1 = v0;
  if (src) {
    const float4* s4 = (const float4*)src;
    v0 = s4[lane * 2]; v1 = s4[lane * 2 + 1];
  }
  float ss = v0.x*v0.x + v0.y*v0.y + v0.z*v0.z + v0.w*v0.w
           + v1.x*v1.x + v1.y*v1.y + v1.z*v1.z + v1.w*v1.w;
  #pragma unroll
  for (int o = 32; o; o >>= 1) ss += __shfl_xor(ss, o);
  float n = sqrtf(ss);
  if (lane == 0) nrm[wid] = n;
  float inv = 1.0f / fmaxf(n, 1e-12f);
  ushort8 o;
  o[0] = f2bf(v0.x * inv); o[1] = f2bf(v0.y * inv); o[2] = f2bf(v0.z * inv); o[3] = f2bf(v0.w * inv);
  o[4] = f2bf(v1.x * inv); o[5] = f2bf(v1.y * inv); o[6] = f2bf(v1.z * inv); o[7] = f2bf(v1.w * inv);
  *(ushort8*)(xn + (size_t)wid * H_ + lane * 8) = o;
}

// ---------------- K2: Gram row-sums (clipped), symmetric: only tiles ti<=tj ----------------
// off-diag tile contributes row-sums -> rr[ti-rows] AND col-sums -> rr[tj-rows]
__global__ __launch_bounds__(256) void k_gram(const unsigned short* __restrict__ xn,
                                              float* __restrict__ r, float* __restrict__ sc) {
  __shared__ __align__(16) unsigned short As[128 * 32];
  __shared__ __align__(16) unsigned short Bs[128 * 32];
  int bid = blockIdx.x;
  int idx = bid % 36, mb = bid / 36;
  int ti = 0, rem = idx;
  while (rem >= 8 - ti) { rem -= 8 - ti; ++ti; }
  int tj = ti + rem;
  bool diag = (ti == tj);
  const unsigned short* X = xn + (size_t)mb * NP * H_;
  int tid = threadIdx.x;
  int w = tid >> 6, lane = tid & 63;
  int wr = w >> 1, wc = w & 1;
  f32x4 acc[4][4] = {};

  int lrow = lane >> 2;   // row within 16-row staging chunk
  int ps0 = lane & 3;     // physical 16B segment

  auto stage = [&](int ks) {
    #pragma unroll
    for (int q = 0; q < 2; ++q) {
      int chunk = w * 2 + q;
      int row = chunk * 16 + lrow;
      int qq = ps0 ^ ((row >> 1) & 3);  // logical k-segment stored at this physical slot
      const unsigned short* gA = X + (size_t)(ti * 128 + row) * H_ + ks * 32 + qq * 8;
      gload16(gA, (void*)(As + chunk * 512));
      if (!diag) {
        const unsigned short* gB = X + (size_t)(tj * 128 + row) * H_ + ks * 32 + qq * 8;
        gload16(gB, (void*)(Bs + chunk * 512));
      }
    }
  };

  const unsigned short* Bsrc = diag ? As : Bs;
  stage(0);
  for (int ks = 0; ks < 16; ++ks) {
    __syncthreads();   // drains vmcnt: staged tile visible
    short8 af[4], bf[4];
    #pragma unroll
    for (int mi = 0; mi < 4; ++mi) {
      int row = wr * 64 + mi * 16 + (lane & 15);
      int ps = (lane >> 4) ^ ((row >> 1) & 3);
      af[mi] = *(const short8*)(As + row * 32 + ps * 8);
    }
    #pragma unroll
    for (int ni = 0; ni < 4; ++ni) {
      int row = wc * 64 + ni * 16 + (lane & 15);
      int ps = (lane >> 4) ^ ((row >> 1) & 3);
      bf[ni] = *(const short8*)(Bsrc + row * 32 + ps * 8);
    }
    #pragma unroll
    for (int mi = 0; mi < 4; ++mi)
      #pragma unroll
      for (int ni = 0; ni < 4; ++ni)
        acc[mi][ni] = __builtin_amdgcn_mfma_f32_16x16x32_bf16(af[mi], bf[ni], acc[mi][ni], 0, 0, 0);
    __syncthreads();   // all reads done before overwrite
    if (ks < 15) stage(ks + 1);
  }

  // epilogue. C/D layout: col = lane&15, row = (lane>>4)*4 + reg (within 16x16 frag)
  float* rr = r + mb * NP;
  // row-sums -> rows of ti-block
  #pragma unroll
  for (int mi = 0; mi < 4; ++mi) {
    #pragma unroll
    for (int reg = 0; reg < 4; ++reg) {
      float v = fmaxf(acc[mi][0][reg], 0.f) + fmaxf(acc[mi][1][reg], 0.f)
              + fmaxf(acc[mi][2][reg], 0.f) + fmaxf(acc[mi][3][reg], 0.f);
      v += __shfl_xor(v, 1); v += __shfl_xor(v, 2); v += __shfl_xor(v, 4); v += __shfl_xor(v, 8);
      if ((lane & 15) == 0) {
        int row = ti * 128 + wr * 64 + mi * 16 + (lane >> 4) * 4 + reg;
        atomicAdd(&rr[row], v);
      }
    }
  }
  // col-sums -> rows of tj-block (symmetry), off-diagonal tiles only
  if (!diag) {
    #pragma unroll
    for (int ni = 0; ni < 4; ++ni) {
      float s = 0.f;
      #pragma unroll
      for (int mi = 0; mi < 4; ++mi)
        #pragma unroll
        for (int reg = 0; reg < 4; ++reg)
          s += fmaxf(acc[mi][ni][reg], 0.f);
      s += __shfl_xor(s, 16); s += __shfl_xor(s, 32);
      if (lane < 16) atomicAdd(&rr[tj * 128 + wc * 64 + ni * 16 + lane], s);
    }
  }
  // row 0 of G -> sc (tiles with ti==0 cover all columns)
  if (ti == 0 && wr == 0 && (lane >> 4) == 0) {
    float* scc = sc + mb * NP;
    #pragma unroll
    for (int ni = 0; ni < 4; ++ni) {
      int col = tj * 128 + wc * 64 + ni * 16 + (lane & 15);
      scc[col] = fmaxf(acc[0][ni][0], 0.f);
    }
  }
}

// ---------------- K3: y[mb][h] = sum_m w[m] * xn[mb][m][h], weights computed inline ----------------
__global__ __launch_bounds__(256) void k_y(const unsigned short* __restrict__ xn,
                                           const float* __restrict__ r, const float* __restrict__ sc,
                                           const float* __restrict__ nrm, float* __restrict__ y) {
  __shared__ float s_w[128];
  int bid = blockIdx.x;
  int chunk = bid & 7, mb = bid >> 3;
  int m0 = chunk * 128;
  int t = threadIdx.x;
  const float* rr = r + mb * NP;
  if (t < 128) {
    int m = m0 + t;
    float wm = 0.f;
    if (m < 1001) {
      float d0 = rsqrtf(rr[0] + 1.0f);
      float dm = rsqrtf(rr[m] + 1.0f);
      wm = d0 * dm * (sc[mb * NP + m] + (m == 0 ? 1.0f : 0.0f)) * nrm[mb * NP + m];
    }
    s_w[t] = wm;
  }
  __syncthreads();
  const unsigned short* X = xn + (size_t)mb * NP * H_ + t * 2;
  float a0 = 0.f, a1 = 0.f;
  for (int i = 0; i < 128; ++i) {
    float wm = s_w[i];
    unsigned u = *(const unsigned*)(X + (size_t)(m0 + i) * H_);
    a0 += wm * bf2f((unsigned short)(u & 0xffff));
    a1 += wm * bf2f((unsigned short)(u >> 16));
  }
  atomicAdd(&y[mb * H_ + 2 * t], a0);
  atomicAdd(&y[mb * H_ + 2 * t + 1], a1);
}

// ---------------- K4: go[b][k] += coef_mod * tanh(y[mb]^T W_mod + b_mod[0])  ----------------
__global__ __launch_bounds__(256) void k_go(const float* __restrict__ y,
                                            const float* __restrict__ Wtt, const float* __restrict__ btt,
                                            const float* __restrict__ Wit, const float* __restrict__ bit,
                                            float* __restrict__ go) {
  int mb = blockIdx.x;           // 0..63
  int b = mb & 31, mod = mb >> 5;
  const float* W = mod ? Wit : Wtt;
  const float* bias = mod ? bit : btt;   // row 0 of [N,H] bias
  float coef = mod ? 0.3f : 0.7f;
  const float* yy = y + mb * H_;
  int t = threadIdx.x;
  #pragma unroll
  for (int k = t; k < H_; k += 256) {
    float a = bias[k];
    for (int h = 0; h < H_; ++h) a = fmaf(yy[h], W[h * H_ + k], a);
    atomicAdd(&go[b * H_ + k], coef * tanh_fast(a));
  }
}

// ---------------- K5: out = 0.5*base + 0.5*graph_o (broadcast over C) ----------------
__global__ __launch_bounds__(256) void k_out(const float* __restrict__ bt, const float* __restrict__ bi,
                                             const float* __restrict__ go, float* __restrict__ out) {
  const float4* bt4 = (const float4*)bt;
  const float4* bi4 = (const float4*)bi;
  const float4* go4 = (const float4*)go;
  float4* o4 = (float4*)out;
  const int n1 = B_ * C_ * (H_ / 4);   // 4,096,000
  int stride = gridDim.x * blockDim.x;
  for (int i = blockIdx.x * blockDim.x + threadIdx.x; i < 2 * n1; i += stride) {
    int v = (i >= n1) ? i - n1 : i;
    float4 base = (i >= n1) ? bi4[v] : bt4[v];
    int b = v / (C_ * (H_ / 4));
    int h4 = v & (H_ / 4 - 1);
    float4 g = go4[b * (H_ / 4) + h4];
    float4 o;
    o.x = 0.5f * (base.x + g.x);
    o.y = 0.5f * (base.y + g.y);
    o.z = 0.5f * (base.z + g.z);
    o.w = 0.5f * (base.w + g.w);
    o4[i] = o;
  }
}

extern "C" void kernel_launch(void* const* d_in, const int* in_sizes, int n_in,
                              void* d_out, int out_size, void* d_ws, size_t ws_size,
                              hipStream_t stream) {
  const float* it  = (const float*)d_in[0];
  const float* ii  = (const float*)d_in[1];
  const float* bt  = (const float*)d_in[2];
  const float* bi  = (const float*)d_in[3];
  const float* Wtt = (const float*)d_in[4];
  const float* btt = (const float*)d_in[5];
  const float* Wit = (const float*)d_in[6];
  const float* bit = (const float*)d_in[7];

  char* ws = (char*)d_ws;
  unsigned short* xn = (unsigned short*)ws;                       // 2*32*1024*512*2 = 67,108,864 B
  size_t off = 67108864;
  float* nrm = (float*)(ws + off); off += 262144;                 // [2][32][1024] f32
  float* sc  = (float*)(ws + off); off += 262144;
  float* r   = (float*)(ws + off); off += 262144;                 // zeroed
  float* y   = (float*)(ws + off); off += 131072;                 // zeroed
  float* go  = (float*)(ws + off); off += 65536;                  // zeroed

  hipMemsetAsync(r, 0, 262144 + 131072 + 65536, stream);          // r,y,go contiguous

  k_norm<<<16384, 256, 0, stream>>>(it, ii, bt, bi, xn, nrm);
  k_gram<<<64 * 36, 256, 0, stream>>>(xn, r, sc);
  k_y<<<512, 256, 0, stream>>>(xn, r, sc, nrm, y);
  k_go<<<64, 256, 0, stream>>>(y, Wtt, btt, Wit, bit, go);
  k_out<<<2048, 256, 0, stream>>>(bt, bi, go, (float*)d_out);
}

// Round 3
// 194.472 us; speedup vs baseline: 1.6229x; 1.1292x over previous
//
#include <hip/hip_runtime.h>
#include <hip/hip_bf16.h>

#define B_ 32
#define C_ 1000
#define H_ 512
#define NP 1024   // padded node count (N=1001 real)

typedef __attribute__((ext_vector_type(8))) short short8;
typedef __attribute__((ext_vector_type(8))) unsigned short ushort8;
typedef __attribute__((ext_vector_type(4))) float f32x4;

__device__ __forceinline__ unsigned short f2bf(float f) {
  unsigned u = __builtin_bit_cast(unsigned, f);
  u += 0x7FFF + ((u >> 16) & 1);
  return (unsigned short)(u >> 16);
}
__device__ __forceinline__ float bf2f(unsigned short h) {
  return __builtin_bit_cast(float, (unsigned)h << 16);
}
__device__ __forceinline__ float tanh_fast(float x) {
  float ax = fminf(fabsf(x), 15.0f);
  float e = __expf(2.0f * ax);
  float t = (e - 1.0f) / (e + 1.0f);
  return copysignf(t, x);
}
__device__ __forceinline__ void gload16(const void* g, void* l) {
  __builtin_amdgcn_global_load_lds((const __attribute__((address_space(1))) unsigned*)g,
                                   (__attribute__((address_space(3))) unsigned*)l, 16, 0, 0);
}

// ---------------- K1: normalize features -> bf16 padded [2][32][1024][512]; also zero r/y/go ----------------
__global__ __launch_bounds__(256) void k_norm(const float* __restrict__ it, const float* __restrict__ ii,
                                              const float* __restrict__ bt, const float* __restrict__ bi,
                                              unsigned short* __restrict__ xn, float* __restrict__ nrm,
                                              float* __restrict__ zero_base) {
  // zero r (65536 f32) + y (32768) + go (16384) = 114688 f32, contiguous at zero_base
  int zi = blockIdx.x * 256 + threadIdx.x;
  if (zi < 114688) zero_base[zi] = 0.0f;

  int wid = blockIdx.x * 4 + (threadIdx.x >> 6);  // one wave per node; wid in [0, 65536)
  int lane = threadIdx.x & 63;
  int node = wid & (NP - 1);
  int mb = wid >> 10;          // mod*32 + b
  int b = mb & 31, mod = mb >> 5;
  const float* src = nullptr;
  if (node == 0) src = (mod ? ii : it) + b * H_;
  else if (node <= C_) src = (mod ? bi : bt) + ((size_t)b * C_ + (node - 1)) * H_;
  float4 v0 = make_float4(0.f, 0.f, 0.f, 0.f), v1 = v0;
  if (src) {
    const float4* s4 = (const float4*)src;
    v0 = s4[lane * 2]; v1 = s4[lane * 2 + 1];
  }
  float ss = v0.x*v0.x + v0.y*v0.y + v0.z*v0.z + v0.w*v0.w
           + v1.x*v1.x + v1.y*v1.y + v1.z*v1.z + v1.w*v1.w;
  #pragma unroll
  for (int o = 32; o; o >>= 1) ss += __shfl_xor(ss, o);
  float n = sqrtf(ss);
  if (lane == 0) nrm[wid] = n;
  float inv = 1.0f / fmaxf(n, 1e-12f);
  ushort8 o;
  o[0] = f2bf(v0.x * inv); o[1] = f2bf(v0.y * inv); o[2] = f2bf(v0.z * inv); o[3] = f2bf(v0.w * inv);
  o[4] = f2bf(v1.x * inv); o[5] = f2bf(v1.y * inv); o[6] = f2bf(v1.z * inv); o[7] = f2bf(v1.w * inv);
  *(ushort8*)(xn + (size_t)wid * H_ + lane * 8) = o;
}

// ---------------- K2: Gram row-sums (clipped), symmetric tiles ti<=tj, double-buffered ----------------
__global__ __launch_bounds__(256) void k_gram(const unsigned short* __restrict__ xn,
                                              float* __restrict__ r, float* __restrict__ sc) {
  __shared__ __align__(16) unsigned short As[2 * 128 * 32];
  __shared__ __align__(16) unsigned short Bs[2 * 128 * 32];
  int orig = blockIdx.x;
  // XCD-aware mapping: all 36 tiles of an mb land consecutively on one XCD (bid%8 round-robin)
  int xcd = orig & 7;
  int k = orig >> 3;                 // [0, 288)
  int mb = xcd + 8 * (k / 36);
  int idx = k % 36;
  int ti = 0, rem = idx;
  while (rem >= 8 - ti) { rem -= 8 - ti; ++ti; }
  int tj = ti + rem;
  bool diag = (ti == tj);
  const unsigned short* X = xn + (size_t)mb * NP * H_;
  int tid = threadIdx.x;
  int w = tid >> 6, lane = tid & 63;
  int wr = w >> 1, wc = w & 1;
  f32x4 acc[4][4] = {};

  int lrow = lane >> 2;   // row within 16-row staging chunk
  int ps0 = lane & 3;     // physical 16B segment

  auto stage = [&](int buf, int ks) {
    #pragma unroll
    for (int q = 0; q < 2; ++q) {
      int chunk = w * 2 + q;
      int row = chunk * 16 + lrow;
      int qq = ps0 ^ ((row >> 1) & 3);  // logical k-segment stored at this physical slot
      const unsigned short* gA = X + (size_t)(ti * 128 + row) * H_ + ks * 32 + qq * 8;
      gload16(gA, (void*)(As + buf * 4096 + chunk * 512));
      if (!diag) {
        const unsigned short* gB = X + (size_t)(tj * 128 + row) * H_ + ks * 32 + qq * 8;
        gload16(gB, (void*)(Bs + buf * 4096 + chunk * 512));
      }
    }
  };

  stage(0, 0);
  int cur = 0;
  for (int ks = 0; ks < 16; ++ks) {
    __syncthreads();            // vmcnt(0): buf[cur] staged; lgkm: prior reads of buf[cur^1] retired
    if (ks < 15) stage(cur ^ 1, ks + 1);   // next tile flies under this tile's compute
    const unsigned short* Ab = As + cur * 4096;
    const unsigned short* Bb = (diag ? As : Bs) + cur * 4096;
    short8 af[4], bf[4];
    #pragma unroll
    for (int mi = 0; mi < 4; ++mi) {
      int row = wr * 64 + mi * 16 + (lane & 15);
      int ps = (lane >> 4) ^ ((row >> 1) & 3);
      af[mi] = *(const short8*)(Ab + row * 32 + ps * 8);
    }
    #pragma unroll
    for (int ni = 0; ni < 4; ++ni) {
      int row = wc * 64 + ni * 16 + (lane & 15);
      int ps = (lane >> 4) ^ ((row >> 1) & 3);
      bf[ni] = *(const short8*)(Bb + row * 32 + ps * 8);
    }
    #pragma unroll
    for (int mi = 0; mi < 4; ++mi)
      #pragma unroll
      for (int ni = 0; ni < 4; ++ni)
        acc[mi][ni] = __builtin_amdgcn_mfma_f32_16x16x32_bf16(af[mi], bf[ni], acc[mi][ni], 0, 0, 0);
    cur ^= 1;
  }

  // epilogue. C/D layout: col = lane&15, row = (lane>>4)*4 + reg (within 16x16 frag)
  float* rr = r + mb * NP;
  // row-sums -> rows of ti-block
  #pragma unroll
  for (int mi = 0; mi < 4; ++mi) {
    #pragma unroll
    for (int reg = 0; reg < 4; ++reg) {
      float v = fmaxf(acc[mi][0][reg], 0.f) + fmaxf(acc[mi][1][reg], 0.f)
              + fmaxf(acc[mi][2][reg], 0.f) + fmaxf(acc[mi][3][reg], 0.f);
      v += __shfl_xor(v, 1); v += __shfl_xor(v, 2); v += __shfl_xor(v, 4); v += __shfl_xor(v, 8);
      if ((lane & 15) == 0) {
        int row = ti * 128 + wr * 64 + mi * 16 + (lane >> 4) * 4 + reg;
        atomicAdd(&rr[row], v);
      }
    }
  }
  // col-sums -> rows of tj-block (symmetry), off-diagonal tiles only
  if (!diag) {
    #pragma unroll
    for (int ni = 0; ni < 4; ++ni) {
      float s = 0.f;
      #pragma unroll
      for (int mi = 0; mi < 4; ++mi)
        #pragma unroll
        for (int reg = 0; reg < 4; ++reg)
          s += fmaxf(acc[mi][ni][reg], 0.f);
      s += __shfl_xor(s, 16); s += __shfl_xor(s, 32);
      if (lane < 16) atomicAdd(&rr[tj * 128 + wc * 64 + ni * 16 + lane], s);
    }
  }
  // row 0 of G -> sc (tiles with ti==0 cover all columns)
  if (ti == 0 && wr == 0 && (lane >> 4) == 0) {
    float* scc = sc + mb * NP;
    #pragma unroll
    for (int ni = 0; ni < 4; ++ni) {
      int col = tj * 128 + wc * 64 + ni * 16 + (lane & 15);
      scc[col] = fmaxf(acc[0][ni][0], 0.f);
    }
  }
}

// ---------------- K3: y[mb][h] = sum_m w[m] * xn[mb][m][h], weights computed inline ----------------
__global__ __launch_bounds__(256) void k_y(const unsigned short* __restrict__ xn,
                                           const float* __restrict__ r, const float* __restrict__ sc,
                                           const float* __restrict__ nrm, float* __restrict__ y) {
  __shared__ float s_w[128];
  int bid = blockIdx.x;
  int chunk = bid & 7, mb = bid >> 3;
  int m0 = chunk * 128;
  int t = threadIdx.x;
  const float* rr = r + mb * NP;
  if (t < 128) {
    int m = m0 + t;
    float wm = 0.f;
    if (m < 1001) {
      float d0 = rsqrtf(rr[0] + 1.0f);
      float dm = rsqrtf(rr[m] + 1.0f);
      wm = d0 * dm * (sc[mb * NP + m] + (m == 0 ? 1.0f : 0.0f)) * nrm[mb * NP + m];
    }
    s_w[t] = wm;
  }
  __syncthreads();
  const unsigned short* X = xn + (size_t)mb * NP * H_ + t * 2;
  float a0 = 0.f, a1 = 0.f;
  for (int i = 0; i < 128; ++i) {
    float wm = s_w[i];
    unsigned u = *(const unsigned*)(X + (size_t)(m0 + i) * H_);
    a0 += wm * bf2f((unsigned short)(u & 0xffff));
    a1 += wm * bf2f((unsigned short)(u >> 16));
  }
  atomicAdd(&y[mb * H_ + 2 * t], a0);
  atomicAdd(&y[mb * H_ + 2 * t + 1], a1);
}

// ---------------- K4: go[b][k] += coef_mod * tanh(y[mb]^T W_mod + b_mod[0])  ----------------
__global__ __launch_bounds__(256) void k_go(const float* __restrict__ y,
                                            const float* __restrict__ Wtt, const float* __restrict__ btt,
                                            const float* __restrict__ Wit, const float* __restrict__ bit,
                                            float* __restrict__ go) {
  int mb = blockIdx.x;           // 0..63
  int b = mb & 31, mod = mb >> 5;
  const float* W = mod ? Wit : Wtt;
  const float* bias = mod ? bit : btt;   // row 0 of [N,H] bias
  float coef = mod ? 0.3f : 0.7f;
  const float* yy = y + mb * H_;
  int t = threadIdx.x;
  #pragma unroll
  for (int k = t; k < H_; k += 256) {
    float a = bias[k];
    for (int h = 0; h < H_; ++h) a = fmaf(yy[h], W[h * H_ + k], a);
    atomicAdd(&go[b * H_ + k], coef * tanh_fast(a));
  }
}

// ---------------- K5: out = 0.5*base + 0.5*graph_o (broadcast over C) ----------------
__global__ __launch_bounds__(256) void k_out(const float* __restrict__ bt, const float* __restrict__ bi,
                                             const float* __restrict__ go, float* __restrict__ out) {
  const float4* bt4 = (const float4*)bt;
  const float4* bi4 = (const float4*)bi;
  const float4* go4 = (const float4*)go;
  float4* o4 = (float4*)out;
  const int n1 = B_ * C_ * (H_ / 4);   // 4,096,000
  int stride = gridDim.x * blockDim.x;
  for (int i = blockIdx.x * blockDim.x + threadIdx.x; i < 2 * n1; i += stride) {
    int v = (i >= n1) ? i - n1 : i;
    float4 base = (i >= n1) ? bi4[v] : bt4[v];
    int b = v / (C_ * (H_ / 4));
    int h4 = v & (H_ / 4 - 1);
    float4 g = go4[b * (H_ / 4) + h4];
    float4 o;
    o.x = 0.5f * (base.x + g.x);
    o.y = 0.5f * (base.y + g.y);
    o.z = 0.5f * (base.z + g.z);
    o.w = 0.5f * (base.w + g.w);
    o4[i] = o;
  }
}

extern "C" void kernel_launch(void* const* d_in, const int* in_sizes, int n_in,
                              void* d_out, int out_size, void* d_ws, size_t ws_size,
                              hipStream_t stream) {
  const float* it  = (const float*)d_in[0];
  const float* ii  = (const float*)d_in[1];
  const float* bt  = (const float*)d_in[2];
  const float* bi  = (const float*)d_in[3];
  const float* Wtt = (const float*)d_in[4];
  const float* btt = (const float*)d_in[5];
  const float* Wit = (const float*)d_in[6];
  const float* bit = (const float*)d_in[7];

  char* ws = (char*)d_ws;
  unsigned short* xn = (unsigned short*)ws;                       // 2*32*1024*512*2 = 67,108,864 B
  size_t off = 67108864;
  float* nrm = (float*)(ws + off); off += 262144;                 // [2][32][1024] f32
  float* sc  = (float*)(ws + off); off += 262144;
  float* r   = (float*)(ws + off); off += 262144;                 // zeroed in k_norm
  float* y   = (float*)(ws + off); off += 131072;                 // zeroed in k_norm
  float* go  = (float*)(ws + off); off += 65536;                  // zeroed in k_norm

  k_norm<<<16384, 256, 0, stream>>>(it, ii, bt, bi, xn, nrm, r /* r,y,go contiguous */);
  k_gram<<<64 * 36, 256, 0, stream>>>(xn, r, sc);
  k_y<<<512, 256, 0, stream>>>(xn, r, sc, nrm, y);
  k_go<<<64, 256, 0, stream>>>(y, Wtt, btt, Wit, bit, go);
  k_out<<<2048, 256, 0, stream>>>(bt, bi, go, (float*)d_out);
}

// Round 4
// 178.283 us; speedup vs baseline: 1.7703x; 1.0908x over previous
//
#include <hip/hip_runtime.h>
#include <hip/hip_bf16.h>

#define B_ 32
#define C_ 1000
#define H_ 512
#define NP 1024   // padded node count (N=1001 real)

typedef __attribute__((ext_vector_type(8))) short short8;
typedef __attribute__((ext_vector_type(8))) unsigned short ushort8;
typedef __attribute__((ext_vector_type(4))) float f32x4;

__device__ __forceinline__ unsigned short f2bf(float f) {
  unsigned u = __builtin_bit_cast(unsigned, f);
  u += 0x7FFF + ((u >> 16) & 1);
  return (unsigned short)(u >> 16);
}
__device__ __forceinline__ float bf2f(unsigned short h) {
  return __builtin_bit_cast(float, (unsigned)h << 16);
}
__device__ __forceinline__ float tanh_fast(float x) {
  float ax = fminf(fabsf(x), 15.0f);
  float e = __expf(2.0f * ax);
  float t = (e - 1.0f) / (e + 1.0f);
  return copysignf(t, x);
}
__device__ __forceinline__ void gload16(const void* g, void* l) {
  __builtin_amdgcn_global_load_lds((const __attribute__((address_space(1))) unsigned*)g,
                                   (__attribute__((address_space(3))) unsigned*)l, 16, 0, 0);
}

// ---------------- K1: normalize features -> bf16 padded [2][32][1024][512]; also zero r/y/go ----------------
__global__ __launch_bounds__(256) void k_norm(const float* __restrict__ it, const float* __restrict__ ii,
                                              const float* __restrict__ bt, const float* __restrict__ bi,
                                              unsigned short* __restrict__ xn, float* __restrict__ nrm,
                                              float* __restrict__ zero_base) {
  // zero r (65536 f32) + y (32768) + go (16384) = 114688 f32, contiguous at zero_base
  int zi = blockIdx.x * 256 + threadIdx.x;
  if (zi < 114688) zero_base[zi] = 0.0f;

  int wid = blockIdx.x * 4 + (threadIdx.x >> 6);  // one wave per node; wid in [0, 65536)
  int lane = threadIdx.x & 63;
  int node = wid & (NP - 1);
  int mb = wid >> 10;          // mod*32 + b
  int b = mb & 31, mod = mb >> 5;
  const float* src = nullptr;
  if (node == 0) src = (mod ? ii : it) + b * H_;
  else if (node <= C_) src = (mod ? bi : bt) + ((size_t)b * C_ + (node - 1)) * H_;
  float4 v0 = make_float4(0.f, 0.f, 0.f, 0.f), v1 = v0;
  if (src) {
    const float4* s4 = (const float4*)src;
    v0 = s4[lane * 2]; v1 = s4[lane * 2 + 1];
  }
  float ss = v0.x*v0.x + v0.y*v0.y + v0.z*v0.z + v0.w*v0.w
           + v1.x*v1.x + v1.y*v1.y + v1.z*v1.z + v1.w*v1.w;
  #pragma unroll
  for (int o = 32; o; o >>= 1) ss += __shfl_xor(ss, o);
  float n = sqrtf(ss);
  if (lane == 0) nrm[wid] = n;
  float inv = 1.0f / fmaxf(n, 1e-12f);
  ushort8 o;
  o[0] = f2bf(v0.x * inv); o[1] = f2bf(v0.y * inv); o[2] = f2bf(v0.z * inv); o[3] = f2bf(v0.w * inv);
  o[4] = f2bf(v1.x * inv); o[5] = f2bf(v1.y * inv); o[6] = f2bf(v1.z * inv); o[7] = f2bf(v1.w * inv);
  *(ushort8*)(xn + (size_t)wid * H_ + lane * 8) = o;
}

// ---------------- K2: Gram row-sums (clipped), symmetric tiles ti<=tj, double-buffered ----------------
__global__ __launch_bounds__(256) void k_gram(const unsigned short* __restrict__ xn,
                                              float* __restrict__ r, float* __restrict__ sc) {
  __shared__ __align__(16) unsigned short As[2 * 128 * 32];
  __shared__ __align__(16) unsigned short Bs[2 * 128 * 32];
  int orig = blockIdx.x;
  // XCD-aware mapping: all 36 tiles of an mb land consecutively on one XCD (bid%8 round-robin)
  int xcd = orig & 7;
  int k = orig >> 3;                 // [0, 288)
  int mb = xcd + 8 * (k / 36);
  int idx = k % 36;
  int ti = 0, rem = idx;
  while (rem >= 8 - ti) { rem -= 8 - ti; ++ti; }
  int tj = ti + rem;
  bool diag = (ti == tj);
  const unsigned short* X = xn + (size_t)mb * NP * H_;
  int tid = threadIdx.x;
  int w = tid >> 6, lane = tid & 63;
  int wr = w >> 1, wc = w & 1;
  f32x4 acc[4][4] = {};

  int lrow = lane >> 2;   // row within 16-row staging chunk
  int ps0 = lane & 3;     // physical 16B segment

  auto stage = [&](int buf, int ks) {
    #pragma unroll
    for (int q = 0; q < 2; ++q) {
      int chunk = w * 2 + q;
      int row = chunk * 16 + lrow;
      int qq = ps0 ^ ((row >> 1) & 3);  // logical k-segment stored at this physical slot
      const unsigned short* gA = X + (size_t)(ti * 128 + row) * H_ + ks * 32 + qq * 8;
      gload16(gA, (void*)(As + buf * 4096 + chunk * 512));
      if (!diag) {
        const unsigned short* gB = X + (size_t)(tj * 128 + row) * H_ + ks * 32 + qq * 8;
        gload16(gB, (void*)(Bs + buf * 4096 + chunk * 512));
      }
    }
  };

  stage(0, 0);
  int cur = 0;
  for (int ks = 0; ks < 16; ++ks) {
    __syncthreads();            // vmcnt(0): buf[cur] staged; lgkm: prior reads of buf[cur^1] retired
    if (ks < 15) stage(cur ^ 1, ks + 1);   // next tile flies under this tile's compute
    const unsigned short* Ab = As + cur * 4096;
    const unsigned short* Bb = (diag ? As : Bs) + cur * 4096;
    short8 af[4], bf[4];
    #pragma unroll
    for (int mi = 0; mi < 4; ++mi) {
      int row = wr * 64 + mi * 16 + (lane & 15);
      int ps = (lane >> 4) ^ ((row >> 1) & 3);
      af[mi] = *(const short8*)(Ab + row * 32 + ps * 8);
    }
    #pragma unroll
    for (int ni = 0; ni < 4; ++ni) {
      int row = wc * 64 + ni * 16 + (lane & 15);
      int ps = (lane >> 4) ^ ((row >> 1) & 3);
      bf[ni] = *(const short8*)(Bb + row * 32 + ps * 8);
    }
    #pragma unroll
    for (int mi = 0; mi < 4; ++mi)
      #pragma unroll
      for (int ni = 0; ni < 4; ++ni)
        acc[mi][ni] = __builtin_amdgcn_mfma_f32_16x16x32_bf16(af[mi], bf[ni], acc[mi][ni], 0, 0, 0);
    cur ^= 1;
  }

  // epilogue. C/D layout: col = lane&15, row = (lane>>4)*4 + reg (within 16x16 frag)
  float* rr = r + mb * NP;
  // row-sums -> rows of ti-block
  #pragma unroll
  for (int mi = 0; mi < 4; ++mi) {
    #pragma unroll
    for (int reg = 0; reg < 4; ++reg) {
      float v = fmaxf(acc[mi][0][reg], 0.f) + fmaxf(acc[mi][1][reg], 0.f)
              + fmaxf(acc[mi][2][reg], 0.f) + fmaxf(acc[mi][3][reg], 0.f);
      v += __shfl_xor(v, 1); v += __shfl_xor(v, 2); v += __shfl_xor(v, 4); v += __shfl_xor(v, 8);
      if ((lane & 15) == 0) {
        int row = ti * 128 + wr * 64 + mi * 16 + (lane >> 4) * 4 + reg;
        atomicAdd(&rr[row], v);
      }
    }
  }
  // col-sums -> rows of tj-block (symmetry), off-diagonal tiles only
  if (!diag) {
    #pragma unroll
    for (int ni = 0; ni < 4; ++ni) {
      float s = 0.f;
      #pragma unroll
      for (int mi = 0; mi < 4; ++mi)
        #pragma unroll
        for (int reg = 0; reg < 4; ++reg)
          s += fmaxf(acc[mi][ni][reg], 0.f);
      s += __shfl_xor(s, 16); s += __shfl_xor(s, 32);
      if (lane < 16) atomicAdd(&rr[tj * 128 + wc * 64 + ni * 16 + lane], s);
    }
  }
  // row 0 of G -> sc (tiles with ti==0 cover all columns)
  if (ti == 0 && wr == 0 && (lane >> 4) == 0) {
    float* scc = sc + mb * NP;
    #pragma unroll
    for (int ni = 0; ni < 4; ++ni) {
      int col = tj * 128 + wc * 64 + ni * 16 + (lane & 15);
      scc[col] = fmaxf(acc[0][ni][0], 0.f);
    }
  }
}

// ---------------- K3: y[mb][h] = sum_m w[m] * xn[mb][m][h]; ushort8 reads, LDS partials ----------------
__global__ __launch_bounds__(256) void k_y(const unsigned short* __restrict__ xn,
                                           const float* __restrict__ r, const float* __restrict__ sc,
                                           const float* __restrict__ nrm, float* __restrict__ y) {
  __shared__ float s_w[128];
  __shared__ __align__(16) float s_part[4][512];
  int bid = blockIdx.x;
  int chunk = bid & 7, mb = bid >> 3;
  int m0 = chunk * 128;
  int t = threadIdx.x;
  const float* rr = r + mb * NP;
  if (t < 128) {
    int m = m0 + t;
    float wm = 0.f;
    if (m < 1001) {
      float d0 = rsqrtf(rr[0] + 1.0f);
      float dm = rsqrtf(rr[m] + 1.0f);
      wm = d0 * dm * (sc[mb * NP + m] + (m == 0 ? 1.0f : 0.0f)) * nrm[mb * NP + m];
    }
    s_w[t] = wm;
  }
  __syncthreads();
  int w = t >> 6, lane = t & 63;
  float a[8] = {};
  const unsigned short* X = xn + (size_t)mb * NP * H_ + lane * 8;
  for (int i = 0; i < 32; ++i) {
    int m = w * 32 + i;
    float wm = s_w[m];
    ushort8 v = *(const ushort8*)(X + (size_t)(m0 + m) * H_);
    #pragma unroll
    for (int j = 0; j < 8; ++j) a[j] = fmaf(wm, bf2f(v[j]), a[j]);
  }
  f32x4 p0 = {a[0], a[1], a[2], a[3]}, p1 = {a[4], a[5], a[6], a[7]};
  *(f32x4*)&s_part[w][lane * 8] = p0;
  *(f32x4*)&s_part[w][lane * 8 + 4] = p1;
  __syncthreads();
  float v0 = s_part[0][t] + s_part[1][t] + s_part[2][t] + s_part[3][t];
  float v1 = s_part[0][t + 256] + s_part[1][t + 256] + s_part[2][t + 256] + s_part[3][t + 256];
  atomicAdd(&y[mb * H_ + t], v0);
  atomicAdd(&y[mb * H_ + t + 256], v1);
}

// ---------------- K4: go[b][k] += coef_mod * tanh(y[mb]^T W_mod + b_mod[0])  ----------------
__global__ __launch_bounds__(256) void k_go(const float* __restrict__ y,
                                            const float* __restrict__ Wtt, const float* __restrict__ btt,
                                            const float* __restrict__ Wit, const float* __restrict__ bit,
                                            float* __restrict__ go) {
  int mb = blockIdx.x;           // 0..63
  int b = mb & 31, mod = mb >> 5;
  const float* W = mod ? Wit : Wtt;
  const float* bias = mod ? bit : btt;   // row 0 of [N,H] bias
  float coef = mod ? 0.3f : 0.7f;
  const float* yy = y + mb * H_;
  int t = threadIdx.x;
  #pragma unroll
  for (int k = t; k < H_; k += 256) {
    float a = bias[k];
    for (int h = 0; h < H_; ++h) a = fmaf(yy[h], W[h * H_ + k], a);
    atomicAdd(&go[b * H_ + k], coef * tanh_fast(a));
  }
}

// ---------------- K5: out = 0.5*(nrm*xn) + 0.5*graph_o  (base reconstructed from bf16 xn) ----------------
__global__ __launch_bounds__(256) void k_out(const unsigned short* __restrict__ xn,
                                             const float* __restrict__ nrm,
                                             const float* __restrict__ go, float* __restrict__ out) {
  int wid = blockIdx.x * 4 + (threadIdx.x >> 6);  // [0, 64000): one wave per (mod,b,c) row
  int lane = threadIdx.x & 63;
  int mod = wid >= 32000 ? 1 : 0;
  int rrow = wid - mod * 32000;
  int b = rrow / 1000;
  int c = rrow - b * 1000;
  int mb = mod * 32 + b;
  size_t node_off = (size_t)(mb * NP + c + 1);
  float half_n = 0.5f * nrm[node_off];
  ushort8 x = *(const ushort8*)(xn + node_off * H_ + lane * 8);
  const float4* g4 = (const float4*)(go + b * H_ + lane * 8);
  float4 g0 = g4[0], g1 = g4[1];
  float4 o0, o1;
  o0.x = fmaf(half_n, bf2f(x[0]), 0.5f * g0.x);
  o0.y = fmaf(half_n, bf2f(x[1]), 0.5f * g0.y);
  o0.z = fmaf(half_n, bf2f(x[2]), 0.5f * g0.z);
  o0.w = fmaf(half_n, bf2f(x[3]), 0.5f * g0.w);
  o1.x = fmaf(half_n, bf2f(x[4]), 0.5f * g1.x);
  o1.y = fmaf(half_n, bf2f(x[5]), 0.5f * g1.y);
  o1.z = fmaf(half_n, bf2f(x[6]), 0.5f * g1.z);
  o1.w = fmaf(half_n, bf2f(x[7]), 0.5f * g1.w);
  float4* o4 = (float4*)(out + (size_t)wid * H_ + lane * 8);
  o4[0] = o0; o4[1] = o1;
}

extern "C" void kernel_launch(void* const* d_in, const int* in_sizes, int n_in,
                              void* d_out, int out_size, void* d_ws, size_t ws_size,
                              hipStream_t stream) {
  const float* it  = (const float*)d_in[0];
  const float* ii  = (const float*)d_in[1];
  const float* bt  = (const float*)d_in[2];
  const float* bi  = (const float*)d_in[3];
  const float* Wtt = (const float*)d_in[4];
  const float* btt = (const float*)d_in[5];
  const float* Wit = (const float*)d_in[6];
  const float* bit = (const float*)d_in[7];

  char* ws = (char*)d_ws;
  unsigned short* xn = (unsigned short*)ws;                       // 2*32*1024*512*2 = 67,108,864 B
  size_t off = 67108864;
  float* nrm = (float*)(ws + off); off += 262144;                 // [2][32][1024] f32
  float* sc  = (float*)(ws + off); off += 262144;
  float* r   = (float*)(ws + off); off += 262144;                 // zeroed in k_norm
  float* y   = (float*)(ws + off); off += 131072;                 // zeroed in k_norm
  float* go  = (float*)(ws + off); off += 65536;                  // zeroed in k_norm

  k_norm<<<16384, 256, 0, stream>>>(it, ii, bt, bi, xn, nrm, r /* r,y,go contiguous */);
  k_gram<<<64 * 36, 256, 0, stream>>>(xn, r, sc);
  k_y<<<512, 256, 0, stream>>>(xn, r, sc, nrm, y);
  k_go<<<64, 256, 0, stream>>>(y, Wtt, btt, Wit, bit, go);
  k_out<<<16000, 256, 0, stream>>>(xn, nrm, go, (float*)d_out);
}

// Round 5
// 143.646 us; speedup vs baseline: 2.1972x; 1.2411x over previous
//
#include <hip/hip_runtime.h>
#include <hip/hip_bf16.h>

#define B_ 32
#define C_ 1000
#define H_ 512
#define NP 1024   // padded node count (N=1001 real)

typedef __attribute__((ext_vector_type(4))) int i32x4;

__device__ __forceinline__ float tanh_fast(float x) {
  float ax = fminf(fabsf(x), 15.0f);
  float e = __expf(2.0f * ax);
  float t = (e - 1.0f) / (e + 1.0f);
  return copysignf(t, x);
}
__device__ __forceinline__ void gload16(const void* g, void* l) {
  __builtin_amdgcn_global_load_lds((const __attribute__((address_space(1))) unsigned*)g,
                                   (__attribute__((address_space(3))) unsigned*)l, 16, 0, 0);
}
__device__ __forceinline__ float sc2f(unsigned v) {   // sext low byte -> float
  return (float)(int)(signed char)v;
}

// ---------------- K1: normalize -> per-node i8 quant [2][32][1024][512]; zero r/y/go ----------------
__global__ __launch_bounds__(256) void k_norm(const float* __restrict__ it, const float* __restrict__ ii,
                                              const float* __restrict__ bt, const float* __restrict__ bi,
                                              signed char* __restrict__ xq, float* __restrict__ nrm,
                                              float* __restrict__ qs, float* __restrict__ zero_base) {
  int zi = blockIdx.x * 256 + threadIdx.x;
  if (zi < 114688) zero_base[zi] = 0.0f;   // r + y + go contiguous

  int wid = blockIdx.x * 4 + (threadIdx.x >> 6);  // one wave per node
  int lane = threadIdx.x & 63;
  int node = wid & (NP - 1);
  int mb = wid >> 10;
  int b = mb & 31, mod = mb >> 5;
  const float* src = nullptr;
  if (node == 0) src = (mod ? ii : it) + b * H_;
  else if (node <= C_) src = (mod ? bi : bt) + ((size_t)b * C_ + (node - 1)) * H_;
  float4 v0 = make_float4(0.f, 0.f, 0.f, 0.f), v1 = v0;
  if (src) {
    const float4* s4 = (const float4*)src;
    v0 = s4[lane * 2]; v1 = s4[lane * 2 + 1];
  }
  float ss = v0.x*v0.x + v0.y*v0.y + v0.z*v0.z + v0.w*v0.w
           + v1.x*v1.x + v1.y*v1.y + v1.z*v1.z + v1.w*v1.w;
  #pragma unroll
  for (int o = 32; o; o >>= 1) ss += __shfl_xor(ss, o);
  float n = sqrtf(ss);
  if (lane == 0) nrm[wid] = n;
  float inv = 1.0f / fmaxf(n, 1e-12f);
  float x[8] = {v0.x*inv, v0.y*inv, v0.z*inv, v0.w*inv, v1.x*inv, v1.y*inv, v1.z*inv, v1.w*inv};
  float m8 = 0.f;
  #pragma unroll
  for (int j = 0; j < 8; ++j) m8 = fmaxf(m8, fabsf(x[j]));
  #pragma unroll
  for (int o = 32; o; o >>= 1) m8 = fmaxf(m8, __shfl_xor(m8, o));
  if (lane == 0) qs[wid] = m8 * (1.0f / 127.0f);
  float invq = (m8 > 0.f) ? 127.0f / m8 : 0.f;
  int q[8];
  #pragma unroll
  for (int j = 0; j < 8; ++j) q[j] = __float2int_rn(x[j] * invq);
  unsigned lo = (q[0] & 255) | ((q[1] & 255) << 8) | ((q[2] & 255) << 16) | ((unsigned)(q[3] & 255) << 24);
  unsigned hi = (q[4] & 255) | ((q[5] & 255) << 8) | ((q[6] & 255) << 16) | ((unsigned)(q[7] & 255) << 24);
  *(uint2*)(xq + (size_t)wid * H_ + lane * 8) = make_uint2(lo, hi);
}

// ---------------- K2: i8 Gram row-sums (clipped, dequant in epilogue), symmetric ti<=tj, dbuf ----------------
__global__ __launch_bounds__(256) void k_gram(const signed char* __restrict__ xq,
                                              const float* __restrict__ qs,
                                              float* __restrict__ r, float* __restrict__ sc) {
  __shared__ __align__(16) unsigned char As[2 * 128 * 64];
  __shared__ __align__(16) unsigned char Bs[2 * 128 * 64];
  __shared__ float s_qs[256];
  int orig = blockIdx.x;
  int xcd = orig & 7;                // all 36 tiles of an mb on one XCD
  int k = orig >> 3;
  int mb = xcd + 8 * (k / 36);
  int idx = k % 36;
  int ti = 0, rem = idx;
  while (rem >= 8 - ti) { rem -= 8 - ti; ++ti; }
  int tj = ti + rem;
  bool diag = (ti == tj);
  const signed char* X = xq + (size_t)mb * NP * H_;
  int tid = threadIdx.x;
  int w = tid >> 6, lane = tid & 63;
  int wr = w >> 1, wc = w & 1;

  if (tid < 128) s_qs[tid] = qs[mb * NP + ti * 128 + tid];
  else           s_qs[tid] = qs[mb * NP + tj * 128 + (tid - 128)];

  i32x4 acc[4][4] = {};
  int lrow = lane >> 2;   // row within 16-row staging chunk
  int ps0 = lane & 3;     // physical 16B segment

  auto stage = [&](int buf, int ks) {
    #pragma unroll
    for (int q = 0; q < 2; ++q) {
      int chunk = w * 2 + q;
      int row = chunk * 16 + lrow;
      int qq = ps0 ^ ((row >> 1) & 3);  // logical k-segment at this physical slot
      gload16(X + (size_t)(ti * 128 + row) * H_ + ks * 64 + qq * 16,
              (void*)(As + buf * 8192 + chunk * 1024));
      if (!diag)
        gload16(X + (size_t)(tj * 128 + row) * H_ + ks * 64 + qq * 16,
                (void*)(Bs + buf * 8192 + chunk * 1024));
    }
  };

  stage(0, 0);
  int cur = 0;
  for (int ks = 0; ks < 8; ++ks) {          // K = 8 steps x 64
    __syncthreads();                        // vmcnt(0): buf[cur] staged
    if (ks < 7) stage(cur ^ 1, ks + 1);     // next tile flies under compute
    const unsigned char* Ab = As + cur * 8192;
    const unsigned char* Bb = (diag ? As : Bs) + cur * 8192;
    i32x4 af[4], bf[4];
    #pragma unroll
    for (int mi = 0; mi < 4; ++mi) {
      int row = wr * 64 + mi * 16 + (lane & 15);
      int ps = (lane >> 4) ^ ((row >> 1) & 3);
      af[mi] = *(const i32x4*)(Ab + row * 64 + ps * 16);
    }
    #pragma unroll
    for (int ni = 0; ni < 4; ++ni) {
      int row = wc * 64 + ni * 16 + (lane & 15);
      int ps = (lane >> 4) ^ ((row >> 1) & 3);
      bf[ni] = *(const i32x4*)(Bb + row * 64 + ps * 16);
    }
    #pragma unroll
    for (int mi = 0; mi < 4; ++mi)
      #pragma unroll
      for (int ni = 0; ni < 4; ++ni)
        acc[mi][ni] = __builtin_amdgcn_mfma_i32_16x16x64_i8(af[mi], bf[ni], acc[mi][ni], 0, 0, 0);
    cur ^= 1;
  }

  // epilogue: clip (int), dequant via qs, row/col sums. C/D: col=lane&15, row=(lane>>4)*4+reg
  float* rr = r + mb * NP;
  float qsc[4];
  #pragma unroll
  for (int ni = 0; ni < 4; ++ni) qsc[ni] = s_qs[128 + wc * 64 + ni * 16 + (lane & 15)];
  #pragma unroll
  for (int mi = 0; mi < 4; ++mi) {
    #pragma unroll
    for (int reg = 0; reg < 4; ++reg) {
      float v = 0.f;
      #pragma unroll
      for (int ni = 0; ni < 4; ++ni) {
        int d = acc[mi][ni][reg];
        v += (d > 0 ? (float)d : 0.f) * qsc[ni];
      }
      v += __shfl_xor(v, 1); v += __shfl_xor(v, 2); v += __shfl_xor(v, 4); v += __shfl_xor(v, 8);
      if ((lane & 15) == 0) {
        int rloc = wr * 64 + mi * 16 + (lane >> 4) * 4 + reg;
        atomicAdd(&rr[ti * 128 + rloc], v * s_qs[rloc]);
      }
    }
  }
  if (!diag) {
    #pragma unroll
    for (int ni = 0; ni < 4; ++ni) {
      float s = 0.f;
      #pragma unroll
      for (int mi = 0; mi < 4; ++mi)
        #pragma unroll
        for (int reg = 0; reg < 4; ++reg) {
          int d = acc[mi][ni][reg];
          s += (d > 0 ? (float)d : 0.f) * s_qs[wr * 64 + mi * 16 + (lane >> 4) * 4 + reg];
        }
      s += __shfl_xor(s, 16); s += __shfl_xor(s, 32);
      if (lane < 16) {
        int cloc = wc * 64 + ni * 16 + lane;
        atomicAdd(&rr[tj * 128 + cloc], s * s_qs[128 + cloc]);
      }
    }
  }
  if (ti == 0 && wr == 0 && (lane >> 4) == 0) {
    float q0 = s_qs[0];
    float* scc = sc + mb * NP;
    #pragma unroll
    for (int ni = 0; ni < 4; ++ni) {
      int col = tj * 128 + wc * 64 + ni * 16 + (lane & 15);
      int d = acc[0][ni][0];                    // row 0 of G
      scc[col] = (d > 0 ? (float)d : 0.f) * q0 * qsc[ni];
    }
  }
}

// ---------------- K3: y[mb][h] = sum_m w[m] * q[mb][m][h]; w folds d0*dm*(sc+I)*nrm*qs ----------------
__global__ __launch_bounds__(256) void k_y(const signed char* __restrict__ xq,
                                           const float* __restrict__ r, const float* __restrict__ sc,
                                           const float* __restrict__ nrm, const float* __restrict__ qs,
                                           float* __restrict__ y) {
  __shared__ float s_w[128];
  __shared__ __align__(16) float s_part[4][512];
  int bid = blockIdx.x;
  int chunk = bid & 7, mb = bid >> 3;
  int m0 = chunk * 128;
  int t = threadIdx.x;
  const float* rr = r + mb * NP;
  if (t < 128) {
    int m = m0 + t;
    float wm = 0.f;
    if (m < 1001) {
      float d0 = rsqrtf(rr[0] + 1.0f);
      float dm = rsqrtf(rr[m] + 1.0f);
      wm = d0 * dm * (sc[mb * NP + m] + (m == 0 ? 1.0f : 0.0f)) * nrm[mb * NP + m] * qs[mb * NP + m];
    }
    s_w[t] = wm;
  }
  __syncthreads();
  int w = t >> 6, lane = t & 63;
  float a[8] = {};
  const signed char* X = xq + (size_t)mb * NP * H_ + lane * 8;
  for (int i = 0; i < 32; ++i) {
    int m = w * 32 + i;
    float wm = s_w[m];
    uint2 v = *(const uint2*)(X + (size_t)(m0 + m) * H_);
    a[0] = fmaf(wm, sc2f(v.x), a[0]);
    a[1] = fmaf(wm, sc2f(v.x >> 8), a[1]);
    a[2] = fmaf(wm, sc2f(v.x >> 16), a[2]);
    a[3] = fmaf(wm, sc2f(v.x >> 24), a[3]);
    a[4] = fmaf(wm, sc2f(v.y), a[4]);
    a[5] = fmaf(wm, sc2f(v.y >> 8), a[5]);
    a[6] = fmaf(wm, sc2f(v.y >> 16), a[6]);
    a[7] = fmaf(wm, sc2f(v.y >> 24), a[7]);
  }
  #pragma unroll
  for (int j = 0; j < 4; ++j) s_part[w][lane * 8 + j] = a[j];
  #pragma unroll
  for (int j = 4; j < 8; ++j) s_part[w][lane * 8 + j] = a[j];
  __syncthreads();
  float v0 = s_part[0][t] + s_part[1][t] + s_part[2][t] + s_part[3][t];
  float v1 = s_part[0][t + 256] + s_part[1][t + 256] + s_part[2][t + 256] + s_part[3][t + 256];
  atomicAdd(&y[mb * H_ + t], v0);
  atomicAdd(&y[mb * H_ + t + 256], v1);
}

// ---------------- K4: go[b][k] += coef_mod * tanh(y[mb]^T W_mod + b_mod[0]) ----------------
__global__ __launch_bounds__(256) void k_go(const float* __restrict__ y,
                                            const float* __restrict__ Wtt, const float* __restrict__ btt,
                                            const float* __restrict__ Wit, const float* __restrict__ bit,
                                            float* __restrict__ go) {
  int mb = blockIdx.x;           // 0..63
  int b = mb & 31, mod = mb >> 5;
  const float* W = mod ? Wit : Wtt;
  const float* bias = mod ? bit : btt;
  float coef = mod ? 0.3f : 0.7f;
  const float* yy = y + mb * H_;
  int t = threadIdx.x;
  #pragma unroll
  for (int k = t; k < H_; k += 256) {
    float a = bias[k];
    for (int h = 0; h < H_; ++h) a = fmaf(yy[h], W[h * H_ + k], a);
    atomicAdd(&go[b * H_ + k], coef * tanh_fast(a));
  }
}

// ---------------- K5: out = 0.5*(nrm*qs*q) + 0.5*graph_o ----------------
__global__ __launch_bounds__(256) void k_out(const signed char* __restrict__ xq,
                                             const float* __restrict__ nrm, const float* __restrict__ qs,
                                             const float* __restrict__ go, float* __restrict__ out) {
  int wid = blockIdx.x * 4 + (threadIdx.x >> 6);  // [0, 64000)
  int lane = threadIdx.x & 63;
  int mod = wid >= 32000 ? 1 : 0;
  int rrow = wid - mod * 32000;
  int b = rrow / 1000;
  int c = rrow - b * 1000;
  int mb = mod * 32 + b;
  size_t node_off = (size_t)(mb * NP + c + 1);
  float hnq = 0.5f * nrm[node_off] * qs[node_off];
  uint2 x = *(const uint2*)(xq + node_off * H_ + lane * 8);
  const float4* g4 = (const float4*)(go + b * H_ + lane * 8);
  float4 g0 = g4[0], g1 = g4[1];
  float4 o0, o1;
  o0.x = fmaf(hnq, sc2f(x.x), 0.5f * g0.x);
  o0.y = fmaf(hnq, sc2f(x.x >> 8), 0.5f * g0.y);
  o0.z = fmaf(hnq, sc2f(x.x >> 16), 0.5f * g0.z);
  o0.w = fmaf(hnq, sc2f(x.x >> 24), 0.5f * g0.w);
  o1.x = fmaf(hnq, sc2f(x.y), 0.5f * g1.x);
  o1.y = fmaf(hnq, sc2f(x.y >> 8), 0.5f * g1.y);
  o1.z = fmaf(hnq, sc2f(x.y >> 16), 0.5f * g1.z);
  o1.w = fmaf(hnq, sc2f(x.y >> 24), 0.5f * g1.w);
  float4* o4 = (float4*)(out + (size_t)wid * H_ + lane * 8);
  o4[0] = o0; o4[1] = o1;
}

extern "C" void kernel_launch(void* const* d_in, const int* in_sizes, int n_in,
                              void* d_out, int out_size, void* d_ws, size_t ws_size,
                              hipStream_t stream) {
  const float* it  = (const float*)d_in[0];
  const float* ii  = (const float*)d_in[1];
  const float* bt  = (const float*)d_in[2];
  const float* bi  = (const float*)d_in[3];
  const float* Wtt = (const float*)d_in[4];
  const float* btt = (const float*)d_in[5];
  const float* Wit = (const float*)d_in[6];
  const float* bit = (const float*)d_in[7];

  char* ws = (char*)d_ws;
  signed char* xq = (signed char*)ws;                             // 2*32*1024*512 i8 = 33,554,432 B
  size_t off = 33554432;
  float* nrm = (float*)(ws + off); off += 262144;                 // [2][32][1024] f32
  float* qs  = (float*)(ws + off); off += 262144;
  float* sc  = (float*)(ws + off); off += 262144;
  float* r   = (float*)(ws + off); off += 262144;                 // zeroed in k_norm
  float* y   = (float*)(ws + off); off += 131072;                 // zeroed in k_norm
  float* go  = (float*)(ws + off); off += 65536;                  // zeroed in k_norm

  k_norm<<<16384, 256, 0, stream>>>(it, ii, bt, bi, xq, nrm, qs, r /* r,y,go contiguous */);
  k_gram<<<64 * 36, 256, 0, stream>>>(xq, qs, r, sc);
  k_y<<<512, 256, 0, stream>>>(xq, r, sc, nrm, qs, y);
  k_go<<<64, 256, 0, stream>>>(y, Wtt, btt, Wit, bit, go);
  k_out<<<16000, 256, 0, stream>>>(xq, nrm, qs, go, (float*)d_out);
}